// Round 5
// baseline (205.566 us; speedup 1.0000x reference)
//
#include <hip/hip_runtime.h>

#define HH 512
#define WW 512
#define NPLANE 48
#define BY 128
#define CHK 16
#define NCH (BY / CHK)   // 8 chunks per block
#define SLOTS 40         // ring slots per col; 40 = 5*8 keeps quad b128 reads 8-aligned
#define KS 11
#define NBLOCKS (8 * 4 * NPLANE)   // 1536

typedef __attribute__((ext_vector_type(8))) short short8;   // 8 bf16 (A/B frag)
typedef __attribute__((ext_vector_type(4))) float floatx4;  // 4 fp32 (C/D frag)

// exact RNE pack (used once, for weights)
__device__ inline unsigned pk2bf_rne(float a, float b) {
    union { float f; unsigned u; } ua, ub;
    ua.f = a; ub.f = b;
    unsigned lo = (ua.u + 0x7FFFu + ((ua.u >> 16) & 1u)) >> 16;
    unsigned hi = (ub.u + 0x7FFFu + ((ub.u >> 16) & 1u)) >> 16;
    return lo | (hi << 16);
}

// fast round-half-up pack: 2 int adds + 1 v_perm_b32 (CK idiom)
__device__ inline unsigned pkhu(float a, float b) {
    union { float f; unsigned u; } ua, ub;
    ua.f = a; ub.f = b;
    return __builtin_amdgcn_perm(ub.u + 0x8000u, ua.u + 0x8000u, 0x07060302u);
}

// Fully-MFMA SSIM: h-blur = data x W (banded), v-blur = W x ring.
// Each wave owns a private 16-col tile + private LDS ring strip -> no barriers
// in the streaming loop. Intermediates (p,t,p2,t2,pt h-blurred) in bf16.
__global__ __launch_bounds__(256, 4) void ssim_kernel(
    const float* __restrict__ pred, const float* __restrict__ target,
    float* __restrict__ ws_sum, float* __restrict__ out)
{
    // ring[wave][ch][col][slot], bf16: 4*5*16*40*2 = 25600 B
    __shared__ __align__(16) short ring[4][5][16][SLOTS];
    __shared__ float red[4];

    const int tid = threadIdx.x;
    const int wv = tid >> 6;
    const int lane = tid & 63;
    const int m = lane & 15;     // A-row / B-col / C-col index
    const int quad = lane >> 4;  // k-group / C-row-group

    // Gaussian weights, sigma=1.5
    float wsum = 0.f;
#pragma unroll
    for (int k = 0; k < KS; ++k) {
        float d = (float)(k - 5);
        wsum += __expf(-d * d * (1.0f / 4.5f));
    }
    const float invs = 1.0f / wsum;

    // Banded weight fragment: value at k=quad*8+j is w[k - m - 3] (0 outside band).
    // Serves as B in h-mfma (B[k][n]=w[k-n-3]) and A in v-mfma (A[m][k]=w[k-m-3]).
    short8 Wf;
    {
        union { short8 v; unsigned u[4]; } W;
#pragma unroll
        for (int jj = 0; jj < 4; ++jj) {
            float v0, v1;
            {
                int idx = quad * 8 + 2 * jj - m - 3;
                float d = (float)(idx - 5);
                v0 = (idx >= 0 && idx < KS) ? __expf(-d * d * (1.0f / 4.5f)) * invs : 0.f;
            }
            {
                int idx = quad * 8 + 2 * jj + 1 - m - 3;
                float d = (float)(idx - 5);
                v1 = (idx >= 0 && idx < KS) ? __expf(-d * d * (1.0f / 4.5f)) * invs : 0.f;
            }
            W.u[jj] = pk2bf_rne(v0, v1);
        }
        Wf = W.v;
    }

    const size_t poff = (size_t)blockIdx.z * HH * WW;
    const float* __restrict__ pp = pred + poff;
    const float* __restrict__ tp = target + poff;
    const int X0 = blockIdx.x * 64 + wv * 16;  // wave's 16-col tile
    const int rawX = X0 - 8;                   // 32-col raw window base
    const int Y0 = blockIdx.y * BY;

    const float C1 = 1.0e-4f;
    const float C2 = 9.0e-4f;
    float lsum = 0.f;
    const floatx4 z = {0.f, 0.f, 0.f, 0.f};

    // h-step k: produce h-blurred rows [Y0+16k-8, Y0+16k+7] into ring at slot base sb
    auto h_step = [&](int k, int sb) {
        const int row = Y0 + CHK * k - 8 + m;
        const bool rowok = ((unsigned)row < (unsigned)HH);
        const int c0 = rawX + quad * 8;
        float4 p0 = {0, 0, 0, 0}, p1 = {0, 0, 0, 0};
        float4 t0 = {0, 0, 0, 0}, t1 = {0, 0, 0, 0};
        if (rowok) {
            const float* pr = pp + (size_t)row * WW;
            const float* tr = tp + (size_t)row * WW;
            if ((unsigned)c0 < (unsigned)WW) {
                p0 = *(const float4*)(pr + c0);
                t0 = *(const float4*)(tr + c0);
            }
            if ((unsigned)(c0 + 4) < (unsigned)WW) {
                p1 = *(const float4*)(pr + c0 + 4);
                t1 = *(const float4*)(tr + c0 + 4);
            }
        }
        const float p[8] = {p0.x, p0.y, p0.z, p0.w, p1.x, p1.y, p1.z, p1.w};
        const float t[8] = {t0.x, t0.y, t0.z, t0.w, t1.x, t1.y, t1.z, t1.w};
        union { short8 v; unsigned u[4]; } Fp, Ft, Fpp, Ftt, Fpt;
#pragma unroll
        for (int jj = 0; jj < 4; ++jj) {
            const float a0 = p[2 * jj], a1 = p[2 * jj + 1];
            const float b0 = t[2 * jj], b1 = t[2 * jj + 1];
            Fp.u[jj]  = pkhu(a0, a1);
            Ft.u[jj]  = pkhu(b0, b1);
            Fpp.u[jj] = pkhu(a0 * a0, a1 * a1);
            Ftt.u[jj] = pkhu(b0 * b0, b1 * b1);
            Fpt.u[jj] = pkhu(a0 * b0, a1 * b1);
        }
        floatx4 Dp  = __builtin_amdgcn_mfma_f32_16x16x32_bf16(Fp.v,  Wf, z, 0, 0, 0);
        floatx4 Dt  = __builtin_amdgcn_mfma_f32_16x16x32_bf16(Ft.v,  Wf, z, 0, 0, 0);
        floatx4 Dpp = __builtin_amdgcn_mfma_f32_16x16x32_bf16(Fpp.v, Wf, z, 0, 0, 0);
        floatx4 Dtt = __builtin_amdgcn_mfma_f32_16x16x32_bf16(Ftt.v, Wf, z, 0, 0, 0);
        floatx4 Dpt = __builtin_amdgcn_mfma_f32_16x16x32_bf16(Fpt.v, Wf, z, 0, 0, 0);
        // C-layout: col = lane&15 (=m), rows = quad*4 + reg -> slots sb+quad*4+reg
        int slot = sb + quad * 4;
        if (slot >= SLOTS) slot -= SLOTS;
        {
            uint2 v;
            v.x = pkhu(Dp[0], Dp[1]);   v.y = pkhu(Dp[2], Dp[3]);
            *(uint2*)&ring[wv][0][m][slot] = v;
            v.x = pkhu(Dt[0], Dt[1]);   v.y = pkhu(Dt[2], Dt[3]);
            *(uint2*)&ring[wv][1][m][slot] = v;
            v.x = pkhu(Dpp[0], Dpp[1]); v.y = pkhu(Dpp[2], Dpp[3]);
            *(uint2*)&ring[wv][2][m][slot] = v;
            v.x = pkhu(Dtt[0], Dtt[1]); v.y = pkhu(Dtt[2], Dtt[3]);
            *(uint2*)&ring[wv][3][m][slot] = v;
            v.x = pkhu(Dpt[0], Dpt[1]); v.y = pkhu(Dpt[2], Dpt[3]);
            *(uint2*)&ring[wv][4][m][slot] = v;
        }
    };

    // v-step: consume 32-slot window starting at vb -> 16 output rows, SSIM
    auto v_step = [&](int vb) {
        int sq = vb + quad * 8;
        if (sq >= SLOTS) sq -= SLOTS;
        const short8 Bp  = *(const short8*)&ring[wv][0][m][sq];
        const short8 Bt  = *(const short8*)&ring[wv][1][m][sq];
        const short8 Bpp = *(const short8*)&ring[wv][2][m][sq];
        const short8 Btt = *(const short8*)&ring[wv][3][m][sq];
        const short8 Bpt = *(const short8*)&ring[wv][4][m][sq];
        floatx4 Mp  = __builtin_amdgcn_mfma_f32_16x16x32_bf16(Wf, Bp,  z, 0, 0, 0);
        floatx4 Mt  = __builtin_amdgcn_mfma_f32_16x16x32_bf16(Wf, Bt,  z, 0, 0, 0);
        floatx4 Mpp = __builtin_amdgcn_mfma_f32_16x16x32_bf16(Wf, Bpp, z, 0, 0, 0);
        floatx4 Mtt = __builtin_amdgcn_mfma_f32_16x16x32_bf16(Wf, Btt, z, 0, 0, 0);
        floatx4 Mpt = __builtin_amdgcn_mfma_f32_16x16x32_bf16(Wf, Bpt, z, 0, 0, 0);
#pragma unroll
        for (int r = 0; r < 4; ++r) {
            const float mup = Mp[r], mut = Mt[r];
            const float mupsq = mup * mup, mutsq = mut * mut, mucr = mup * mut;
            const float sp2 = Mpp[r] - mupsq;
            const float st2 = Mtt[r] - mutsq;
            const float scr = Mpt[r] - mucr;
            const float n1 = 2.f * mucr + C1;
            const float n2 = 2.f * scr + C2;
            const float d1 = mupsq + mutsq + C1;
            const float d2 = sp2 + st2 + C2;
            lsum += __fdividef(n1 * n2, d1 * d2);
        }
    };

    // Software pipeline: h(0), then { h(i+1); v(i) } -- wave-private, no barriers.
    int hb = SLOTS - 8;  // (-8) mod 40
    int vb = SLOTS - 8;
    h_step(0, hb);
    hb += CHK; if (hb >= SLOTS) hb -= SLOTS;
    for (int i = 0; i < NCH; ++i) {
        h_step(i + 1, hb);
        hb += CHK; if (hb >= SLOTS) hb -= SLOTS;
        v_step(vb);
        vb += CHK; if (vb >= SLOTS) vb -= SLOTS;
    }

    // wave reduce -> block reduce -> one atomic per block -> last block finalizes
#pragma unroll
    for (int off = 32; off > 0; off >>= 1) lsum += __shfl_down(lsum, off, 64);
    if (lane == 0) red[wv] = lsum;
    __syncthreads();
    if (tid == 0) {
        atomicAdd(ws_sum, red[0] + red[1] + red[2] + red[3]);
        __threadfence();
        unsigned prev = atomicAdd((unsigned*)(ws_sum + 1), 1u);
        if (prev == NBLOCKS - 1) {
            float tot = atomicAdd(ws_sum, 0.0f);   // coherent device-scope read
            out[0] = 1.0f - tot * (1.0f / 12582912.0f);  // N = 16*3*512*512
        }
    }
}

extern "C" void kernel_launch(void* const* d_in, const int* in_sizes, int n_in,
                              void* d_out, int out_size, void* d_ws, size_t ws_size,
                              hipStream_t stream) {
    const float* pred = (const float*)d_in[0];
    const float* target = (const float*)d_in[1];
    float* out = (float*)d_out;
    float* ws = (float*)d_ws;

    hipMemsetAsync(ws, 0, 2 * sizeof(float), stream);   // sum + done-counter
    dim3 grid(WW / 64, HH / BY, NPLANE);                // 8 x 4 x 48 = 1536 blocks
    ssim_kernel<<<grid, 256, 0, stream>>>(pred, target, ws, out);
}

// Round 6
// 168.125 us; speedup vs baseline: 1.2227x; 1.2227x over previous
//
#include <hip/hip_runtime.h>

#define HH 512
#define WW 512
#define NPLANE 48
#define BY 128
#define CHK 16
#define NCH (BY / CHK)   // 8 chunks per block
#define SLOTS 40         // logical ring slots (mod-40 indexing; all groups stay aligned)
#define ALLOC 42         // physical pitch: 84 B = 21 dwords (odd) -> <=2-way bank aliasing
#define KS 11

typedef __attribute__((ext_vector_type(8))) short short8;   // 8 bf16 (A/B frag)
typedef __attribute__((ext_vector_type(4))) float floatx4;  // 4 fp32 (C/D frag)

// exact RNE pack (used once, for weights)
__device__ inline unsigned pk2bf_rne(float a, float b) {
    union { float f; unsigned u; } ua, ub;
    ua.f = a; ub.f = b;
    unsigned lo = (ua.u + 0x7FFFu + ((ua.u >> 16) & 1u)) >> 16;
    unsigned hi = (ub.u + 0x7FFFu + ((ub.u >> 16) & 1u)) >> 16;
    return lo | (hi << 16);
}

// fast round-half-up pack: 2 int adds + 1 v_perm_b32 (inputs are non-negative)
__device__ inline unsigned pkhu(float a, float b) {
    union { float f; unsigned u; } ua, ub;
    ua.f = a; ub.f = b;
    return __builtin_amdgcn_perm(ub.u + 0x8000u, ua.u + 0x8000u, 0x07060302u);
}

// Fully-MFMA SSIM: h-blur = data x W (banded), v-blur = W x ring.
// Each wave owns a private 16-col tile + private LDS ring strip -> no barriers
// in the streaming loop. Intermediates (p,t,p2,t2,pt h-blurred) in bf16.
__global__ __launch_bounds__(256, 4) void ssim_kernel(
    const float* __restrict__ pred, const float* __restrict__ target,
    float* __restrict__ ws_sum)
{
    // ring[wave][ch][col][slot], bf16: 4*5*16*42*2 = 26880 B (pitch 21 dwords, odd)
    __shared__ __align__(16) short ring[4][5][16][ALLOC];
    __shared__ float red[4];

    const int tid = threadIdx.x;
    const int wv = tid >> 6;
    const int lane = tid & 63;
    const int m = lane & 15;     // A-row / B-col / C-col index
    const int quad = lane >> 4;  // k-group / C-row-group

    // Gaussian weights, sigma=1.5
    float wsum = 0.f;
#pragma unroll
    for (int k = 0; k < KS; ++k) {
        float d = (float)(k - 5);
        wsum += __expf(-d * d * (1.0f / 4.5f));
    }
    const float invs = 1.0f / wsum;

    // Banded weight fragment: value at k=quad*8+j is w[k - m - 3] (0 outside band).
    // Serves as B in h-mfma (B[k][n]=w[k-n-3]) and A in v-mfma (A[m][k]=w[k-m-3]).
    short8 Wf;
    {
        union { short8 v; unsigned u[4]; } W;
#pragma unroll
        for (int jj = 0; jj < 4; ++jj) {
            float v0, v1;
            {
                int idx = quad * 8 + 2 * jj - m - 3;
                float d = (float)(idx - 5);
                v0 = (idx >= 0 && idx < KS) ? __expf(-d * d * (1.0f / 4.5f)) * invs : 0.f;
            }
            {
                int idx = quad * 8 + 2 * jj + 1 - m - 3;
                float d = (float)(idx - 5);
                v1 = (idx >= 0 && idx < KS) ? __expf(-d * d * (1.0f / 4.5f)) * invs : 0.f;
            }
            W.u[jj] = pk2bf_rne(v0, v1);
        }
        Wf = W.v;
    }

    const size_t poff = (size_t)blockIdx.z * HH * WW;
    const float* __restrict__ pp = pred + poff;
    const float* __restrict__ tp = target + poff;
    const int X0 = blockIdx.x * 64 + wv * 16;  // wave's 16-col tile
    const int rawX = X0 - 8;                   // 32-col raw window base
    const int Y0 = blockIdx.y * BY;

    const float C1 = 1.0e-4f;
    const float C2 = 9.0e-4f;
    float lsum = 0.f;
    const floatx4 z = {0.f, 0.f, 0.f, 0.f};

    // h-step k: produce h-blurred rows [Y0+16k-8, Y0+16k+7] into ring at slot base sb
    auto h_step = [&](int k, int sb) {
        const int row = Y0 + CHK * k - 8 + m;
        const bool rowok = ((unsigned)row < (unsigned)HH);
        const int c0 = rawX + quad * 8;
        float4 p0 = {0, 0, 0, 0}, p1 = {0, 0, 0, 0};
        float4 t0 = {0, 0, 0, 0}, t1 = {0, 0, 0, 0};
        if (rowok) {
            const float* pr = pp + (size_t)row * WW;
            const float* tr = tp + (size_t)row * WW;
            if ((unsigned)c0 < (unsigned)WW) {
                p0 = *(const float4*)(pr + c0);
                t0 = *(const float4*)(tr + c0);
            }
            if ((unsigned)(c0 + 4) < (unsigned)WW) {
                p1 = *(const float4*)(pr + c0 + 4);
                t1 = *(const float4*)(tr + c0 + 4);
            }
        }
        const float p[8] = {p0.x, p0.y, p0.z, p0.w, p1.x, p1.y, p1.z, p1.w};
        const float t[8] = {t0.x, t0.y, t0.z, t0.w, t1.x, t1.y, t1.z, t1.w};
        union { short8 v; unsigned u[4]; } Fp, Ft, Fpp, Ftt, Fpt;
#pragma unroll
        for (int jj = 0; jj < 4; ++jj) {
            const float a0 = p[2 * jj], a1 = p[2 * jj + 1];
            const float b0 = t[2 * jj], b1 = t[2 * jj + 1];
            Fp.u[jj]  = pkhu(a0, a1);
            Ft.u[jj]  = pkhu(b0, b1);
            Fpp.u[jj] = pkhu(a0 * a0, a1 * a1);
            Ftt.u[jj] = pkhu(b0 * b0, b1 * b1);
            Fpt.u[jj] = pkhu(a0 * b0, a1 * b1);
        }
        floatx4 Dp  = __builtin_amdgcn_mfma_f32_16x16x32_bf16(Fp.v,  Wf, z, 0, 0, 0);
        floatx4 Dt  = __builtin_amdgcn_mfma_f32_16x16x32_bf16(Ft.v,  Wf, z, 0, 0, 0);
        floatx4 Dpp = __builtin_amdgcn_mfma_f32_16x16x32_bf16(Fpp.v, Wf, z, 0, 0, 0);
        floatx4 Dtt = __builtin_amdgcn_mfma_f32_16x16x32_bf16(Ftt.v, Wf, z, 0, 0, 0);
        floatx4 Dpt = __builtin_amdgcn_mfma_f32_16x16x32_bf16(Fpt.v, Wf, z, 0, 0, 0);
        // C-layout: col = lane&15 (=m), rows = quad*4 + reg -> slots sb+quad*4+reg
        int slot = sb + quad * 4;
        if (slot >= SLOTS) slot -= SLOTS;
        {
            uint2 v;
            v.x = pkhu(Dp[0], Dp[1]);   v.y = pkhu(Dp[2], Dp[3]);
            *(uint2*)&ring[wv][0][m][slot] = v;
            v.x = pkhu(Dt[0], Dt[1]);   v.y = pkhu(Dt[2], Dt[3]);
            *(uint2*)&ring[wv][1][m][slot] = v;
            v.x = pkhu(Dpp[0], Dpp[1]); v.y = pkhu(Dpp[2], Dpp[3]);
            *(uint2*)&ring[wv][2][m][slot] = v;
            v.x = pkhu(Dtt[0], Dtt[1]); v.y = pkhu(Dtt[2], Dtt[3]);
            *(uint2*)&ring[wv][3][m][slot] = v;
            v.x = pkhu(Dpt[0], Dpt[1]); v.y = pkhu(Dpt[2], Dpt[3]);
            *(uint2*)&ring[wv][4][m][slot] = v;
        }
    };

    // v-step: consume 32-slot window starting at vb -> 16 output rows, SSIM
    auto v_step = [&](int vb) {
        int sq = vb + quad * 8;
        if (sq >= SLOTS) sq -= SLOTS;
        const short8 Bp  = *(const short8*)&ring[wv][0][m][sq];
        const short8 Bt  = *(const short8*)&ring[wv][1][m][sq];
        const short8 Bpp = *(const short8*)&ring[wv][2][m][sq];
        const short8 Btt = *(const short8*)&ring[wv][3][m][sq];
        const short8 Bpt = *(const short8*)&ring[wv][4][m][sq];
        floatx4 Mp  = __builtin_amdgcn_mfma_f32_16x16x32_bf16(Wf, Bp,  z, 0, 0, 0);
        floatx4 Mt  = __builtin_amdgcn_mfma_f32_16x16x32_bf16(Wf, Bt,  z, 0, 0, 0);
        floatx4 Mpp = __builtin_amdgcn_mfma_f32_16x16x32_bf16(Wf, Bpp, z, 0, 0, 0);
        floatx4 Mtt = __builtin_amdgcn_mfma_f32_16x16x32_bf16(Wf, Btt, z, 0, 0, 0);
        floatx4 Mpt = __builtin_amdgcn_mfma_f32_16x16x32_bf16(Wf, Bpt, z, 0, 0, 0);
#pragma unroll
        for (int r = 0; r < 4; ++r) {
            const float mup = Mp[r], mut = Mt[r];
            const float mupsq = mup * mup, mutsq = mut * mut, mucr = mup * mut;
            const float sp2 = Mpp[r] - mupsq;
            const float st2 = Mtt[r] - mutsq;
            const float scr = Mpt[r] - mucr;
            const float n1 = 2.f * mucr + C1;
            const float n2 = 2.f * scr + C2;
            const float d1 = mupsq + mutsq + C1;
            const float d2 = sp2 + st2 + C2;
            lsum += __fdividef(n1 * n2, d1 * d2);
        }
    };

    // Software pipeline: h(0), then { h(i+1); v(i) } -- wave-private, no barriers.
    // Fully unrolled: slot bases are compile-time constants -> ds immediate offsets.
    h_step(0, (SLOTS - 8));                    // rows -8..7 -> slots 32..39,0..7
#pragma unroll
    for (int i = 0; i < NCH; ++i) {
        h_step(i + 1, (CHK * (i + 1) + SLOTS - 8) % SLOTS);
        v_step((CHK * i + SLOTS - 8) % SLOTS);
    }

    // wave reduce -> block reduce -> one atomic per block
#pragma unroll
    for (int off = 32; off > 0; off >>= 1) lsum += __shfl_down(lsum, off, 64);
    if (lane == 0) red[wv] = lsum;
    __syncthreads();
    if (tid == 0) {
        atomicAdd(ws_sum, red[0] + red[1] + red[2] + red[3]);
    }
}

__global__ void finalize_kernel(const float* __restrict__ ws_sum,
                                float* __restrict__ out) {
    out[0] = 1.0f - ws_sum[0] * (1.0f / 12582912.0f);  // N = 16*3*512*512
}

extern "C" void kernel_launch(void* const* d_in, const int* in_sizes, int n_in,
                              void* d_out, int out_size, void* d_ws, size_t ws_size,
                              hipStream_t stream) {
    const float* pred = (const float*)d_in[0];
    const float* target = (const float*)d_in[1];
    float* out = (float*)d_out;
    float* ws = (float*)d_ws;

    hipMemsetAsync(ws, 0, sizeof(float), stream);       // graph-capturable
    dim3 grid(WW / 64, HH / BY, NPLANE);                // 8 x 4 x 48 = 1536 blocks
    ssim_kernel<<<grid, 256, 0, stream>>>(pred, target, ws);
    finalize_kernel<<<1, 1, 0, stream>>>(ws, out);
}

// Round 7
// 142.501 us; speedup vs baseline: 1.4426x; 1.1798x over previous
//
#include <hip/hip_runtime.h>

#define HH 512
#define WW 512
#define NPLANE 48
#define BY 128
#define CHK 16
#define NCH (BY / CHK)   // 8 chunks per block
#define SLOTS 40         // ring slots per col (16B-aligned groups; pitch 40 measured best)
#define KS 11

typedef __attribute__((ext_vector_type(8))) short short8;   // 8 bf16 (A/B frag)
typedef __attribute__((ext_vector_type(4))) float floatx4;  // 4 fp32 (C/D frag)

// exact RNE pack (used once, for weights)
__device__ inline unsigned pk2bf_rne(float a, float b) {
    union { float f; unsigned u; } ua, ub;
    ua.f = a; ub.f = b;
    unsigned lo = (ua.u + 0x7FFFu + ((ua.u >> 16) & 1u)) >> 16;
    unsigned hi = (ub.u + 0x7FFFu + ((ub.u >> 16) & 1u)) >> 16;
    return lo | (hi << 16);
}

// fast round-half-up pack: 2 int adds + 1 v_perm_b32
__device__ inline unsigned pkhu(float a, float b) {
    union { float f; unsigned u; } ua, ub;
    ua.f = a; ub.f = b;
    return __builtin_amdgcn_perm(ub.u + 0x8000u, ua.u + 0x8000u, 0x07060302u);
}

struct Raw { float4 p0, p1, t0, t1; };

// Fully-MFMA SSIM: h-blur = data x W (banded), v-blur = W x ring.
// Wave-private LDS ring strips -> no barriers in the loop.
// Register double-buffer prefetch hides global load latency behind a full
// v-step + h-step of compute.
__global__ __launch_bounds__(256, 4) void ssim_kernel(
    const float* __restrict__ pred, const float* __restrict__ target,
    float* __restrict__ ws_sum)
{
    // ring[wave][ch][col][slot], bf16: 4*5*16*40*2 = 25600 B
    __shared__ __align__(16) short ring[4][5][16][SLOTS];
    __shared__ float red[4];

    const int tid = threadIdx.x;
    const int wv = tid >> 6;
    const int lane = tid & 63;
    const int m = lane & 15;     // A-row / B-col / C-col index
    const int quad = lane >> 4;  // k-group / C-row-group

    // Gaussian weights, sigma=1.5
    float wsum = 0.f;
#pragma unroll
    for (int k = 0; k < KS; ++k) {
        float d = (float)(k - 5);
        wsum += __expf(-d * d * (1.0f / 4.5f));
    }
    const float invs = 1.0f / wsum;

    // Banded weight fragment: value at k=quad*8+j is w[k - m - 3] (0 outside band).
    // Serves as B in h-mfma (B[k][n]=w[k-n-3]) and A in v-mfma (A[m][k]=w[k-m-3]).
    short8 Wf;
    {
        union { short8 v; unsigned u[4]; } W;
#pragma unroll
        for (int jj = 0; jj < 4; ++jj) {
            float v0, v1;
            {
                int idx = quad * 8 + 2 * jj - m - 3;
                float d = (float)(idx - 5);
                v0 = (idx >= 0 && idx < KS) ? __expf(-d * d * (1.0f / 4.5f)) * invs : 0.f;
            }
            {
                int idx = quad * 8 + 2 * jj + 1 - m - 3;
                float d = (float)(idx - 5);
                v1 = (idx >= 0 && idx < KS) ? __expf(-d * d * (1.0f / 4.5f)) * invs : 0.f;
            }
            W.u[jj] = pk2bf_rne(v0, v1);
        }
        Wf = W.v;
    }

    const size_t poff = (size_t)blockIdx.z * HH * WW;
    const float* __restrict__ pp = pred + poff;
    const float* __restrict__ tp = target + poff;
    const int X0 = blockIdx.x * 64 + wv * 16;  // wave's 16-col tile
    const int rawX = X0 - 8;                   // 32-col raw window base
    const int Y0 = blockIdx.y * BY;

    const float C1 = 1.0e-4f;
    const float C2 = 9.0e-4f;
    float lsum = 0.f;
    const floatx4 z = {0.f, 0.f, 0.f, 0.f};

    // load chunk k's raw rows (zero-padded outside the image)
    auto load_raw = [&](int k) -> Raw {
        Raw r;
        r.p0 = make_float4(0, 0, 0, 0); r.p1 = make_float4(0, 0, 0, 0);
        r.t0 = make_float4(0, 0, 0, 0); r.t1 = make_float4(0, 0, 0, 0);
        const int row = Y0 + CHK * k - 8 + m;
        if ((unsigned)row < (unsigned)HH) {
            const float* pr = pp + (size_t)row * WW;
            const float* tr = tp + (size_t)row * WW;
            const int c0 = rawX + quad * 8;
            if ((unsigned)c0 < (unsigned)WW) {
                r.p0 = *(const float4*)(pr + c0);
                r.t0 = *(const float4*)(tr + c0);
            }
            if ((unsigned)(c0 + 4) < (unsigned)WW) {
                r.p1 = *(const float4*)(pr + c0 + 4);
                r.t1 = *(const float4*)(tr + c0 + 4);
            }
        }
        return r;
    };

    // h-step: pack raw -> bf16 frags, 5 MFMA, pack D -> ring at slot base sb
    auto h_step = [&](const Raw& r, int sb) {
        const float p[8] = {r.p0.x, r.p0.y, r.p0.z, r.p0.w,
                            r.p1.x, r.p1.y, r.p1.z, r.p1.w};
        const float t[8] = {r.t0.x, r.t0.y, r.t0.z, r.t0.w,
                            r.t1.x, r.t1.y, r.t1.z, r.t1.w};
        union { short8 v; unsigned u[4]; } Fp, Ft, Fpp, Ftt, Fpt;
#pragma unroll
        for (int jj = 0; jj < 4; ++jj) {
            const float a0 = p[2 * jj], a1 = p[2 * jj + 1];
            const float b0 = t[2 * jj], b1 = t[2 * jj + 1];
            Fp.u[jj]  = pkhu(a0, a1);
            Ft.u[jj]  = pkhu(b0, b1);
            Fpp.u[jj] = pkhu(a0 * a0, a1 * a1);
            Ftt.u[jj] = pkhu(b0 * b0, b1 * b1);
            Fpt.u[jj] = pkhu(a0 * b0, a1 * b1);
        }
        floatx4 Dp  = __builtin_amdgcn_mfma_f32_16x16x32_bf16(Fp.v,  Wf, z, 0, 0, 0);
        floatx4 Dt  = __builtin_amdgcn_mfma_f32_16x16x32_bf16(Ft.v,  Wf, z, 0, 0, 0);
        floatx4 Dpp = __builtin_amdgcn_mfma_f32_16x16x32_bf16(Fpp.v, Wf, z, 0, 0, 0);
        floatx4 Dtt = __builtin_amdgcn_mfma_f32_16x16x32_bf16(Ftt.v, Wf, z, 0, 0, 0);
        floatx4 Dpt = __builtin_amdgcn_mfma_f32_16x16x32_bf16(Fpt.v, Wf, z, 0, 0, 0);
        // C-layout: col = lane&15 (=m), rows = quad*4 + reg -> slots sb+quad*4+reg
        int slot = sb + quad * 4;
        if (slot >= SLOTS) slot -= SLOTS;
        uint2 v;
        v.x = pkhu(Dp[0], Dp[1]);   v.y = pkhu(Dp[2], Dp[3]);
        *(uint2*)&ring[wv][0][m][slot] = v;
        v.x = pkhu(Dt[0], Dt[1]);   v.y = pkhu(Dt[2], Dt[3]);
        *(uint2*)&ring[wv][1][m][slot] = v;
        v.x = pkhu(Dpp[0], Dpp[1]); v.y = pkhu(Dpp[2], Dpp[3]);
        *(uint2*)&ring[wv][2][m][slot] = v;
        v.x = pkhu(Dtt[0], Dtt[1]); v.y = pkhu(Dtt[2], Dtt[3]);
        *(uint2*)&ring[wv][3][m][slot] = v;
        v.x = pkhu(Dpt[0], Dpt[1]); v.y = pkhu(Dpt[2], Dpt[3]);
        *(uint2*)&ring[wv][4][m][slot] = v;
    };

    // v-step: consume 32-slot window starting at vb -> 16 output rows, SSIM
    auto v_step = [&](int vb) {
        int sq = vb + quad * 8;
        if (sq >= SLOTS) sq -= SLOTS;
        const short8 Bp  = *(const short8*)&ring[wv][0][m][sq];
        const short8 Bt  = *(const short8*)&ring[wv][1][m][sq];
        const short8 Bpp = *(const short8*)&ring[wv][2][m][sq];
        const short8 Btt = *(const short8*)&ring[wv][3][m][sq];
        const short8 Bpt = *(const short8*)&ring[wv][4][m][sq];
        floatx4 Mp  = __builtin_amdgcn_mfma_f32_16x16x32_bf16(Wf, Bp,  z, 0, 0, 0);
        floatx4 Mt  = __builtin_amdgcn_mfma_f32_16x16x32_bf16(Wf, Bt,  z, 0, 0, 0);
        floatx4 Mpp = __builtin_amdgcn_mfma_f32_16x16x32_bf16(Wf, Bpp, z, 0, 0, 0);
        floatx4 Mtt = __builtin_amdgcn_mfma_f32_16x16x32_bf16(Wf, Btt, z, 0, 0, 0);
        floatx4 Mpt = __builtin_amdgcn_mfma_f32_16x16x32_bf16(Wf, Bpt, z, 0, 0, 0);
#pragma unroll
        for (int r = 0; r < 4; ++r) {
            const float mup = Mp[r], mut = Mt[r];
            const float mupsq = mup * mup, mutsq = mut * mut, mucr = mup * mut;
            const float sp2 = Mpp[r] - mupsq;
            const float st2 = Mtt[r] - mutsq;
            const float scr = Mpt[r] - mucr;
            const float n1 = 2.f * mucr + C1;
            const float n2 = 2.f * scr + C2;
            const float d1 = mupsq + mutsq + C1;
            const float d2 = sp2 + st2 + C2;
            lsum += __fdividef(n1 * n2, d1 * d2);
        }
    };

    // Software pipeline with register double-buffer prefetch (rolled loop --
    // full unroll spilled to scratch in R6: WRITE_SIZE 48 KB -> 67 MB).
    Raw A = load_raw(0);
    Raw B = load_raw(1);
    int hb = SLOTS - 8;   // (-8) mod 40
    int vb = SLOTS - 8;
    h_step(A, hb);
    hb += CHK; if (hb >= SLOTS) hb -= SLOTS;
#pragma unroll 1
    for (int i = 0; i < NCH; ++i) {
        h_step(B, hb);
        hb += CHK; if (hb >= SLOTS) hb -= SLOTS;
        if (i + 2 <= NCH) B = load_raw(i + 2);   // prefetch overlaps v + next h
        v_step(vb);
        vb += CHK; if (vb >= SLOTS) vb -= SLOTS;
    }

    // wave reduce -> block reduce -> one atomic per block
#pragma unroll
    for (int off = 32; off > 0; off >>= 1) lsum += __shfl_down(lsum, off, 64);
    if (lane == 0) red[wv] = lsum;
    __syncthreads();
    if (tid == 0) {
        atomicAdd(ws_sum, red[0] + red[1] + red[2] + red[3]);
    }
}

__global__ void finalize_kernel(const float* __restrict__ ws_sum,
                                float* __restrict__ out) {
    out[0] = 1.0f - ws_sum[0] * (1.0f / 12582912.0f);  // N = 16*3*512*512
}

extern "C" void kernel_launch(void* const* d_in, const int* in_sizes, int n_in,
                              void* d_out, int out_size, void* d_ws, size_t ws_size,
                              hipStream_t stream) {
    const float* pred = (const float*)d_in[0];
    const float* target = (const float*)d_in[1];
    float* out = (float*)d_out;
    float* ws = (float*)d_ws;

    hipMemsetAsync(ws, 0, sizeof(float), stream);       // graph-capturable
    dim3 grid(WW / 64, HH / BY, NPLANE);                // 8 x 4 x 48 = 1536 blocks
    ssim_kernel<<<grid, 256, 0, stream>>>(pred, target, ws);
    finalize_kernel<<<1, 1, 0, stream>>>(ws, out);
}

// Round 8
// 141.279 us; speedup vs baseline: 1.4550x; 1.0087x over previous
//
#include <hip/hip_runtime.h>

#define HH 512
#define WW 512
#define NPLANE 48
#define BY 128
#define CHK 16
#define NCH (BY / CHK)   // 8 chunks per block
#define SLOTS 40         // ring slots per col (16B-aligned groups; pitch 40 measured best)
#define KS 11

typedef __attribute__((ext_vector_type(8))) short short8;   // 8 bf16 (A/B frag)
typedef __attribute__((ext_vector_type(4))) float floatx4;  // 4 fp32 (C/D frag)

// exact RNE pack (used once, for weights)
__device__ inline unsigned pk2bf_rne(float a, float b) {
    union { float f; unsigned u; } ua, ub;
    ua.f = a; ub.f = b;
    unsigned lo = (ua.u + 0x7FFFu + ((ua.u >> 16) & 1u)) >> 16;
    unsigned hi = (ub.u + 0x7FFFu + ((ub.u >> 16) & 1u)) >> 16;
    return lo | (hi << 16);
}

#if defined(__has_builtin)
#if __has_builtin(__builtin_amdgcn_cvt_pk_bf16_f32)
#define HAVE_CVT_PK_BF16 1
#endif
#endif

// hot-path pack: HW v_cvt_pk_bf16_f32 (1 instr) if available, else
// round-half-up via 2 int adds + v_perm_b32 (3 instrs)
__device__ inline unsigned pkbf(float a, float b) {
#ifdef HAVE_CVT_PK_BF16
    typedef __attribute__((ext_vector_type(2))) __bf16 bf16x2_t;
    bf16x2_t v = __builtin_amdgcn_cvt_pk_bf16_f32(a, b);
    return __builtin_bit_cast(unsigned, v);
#else
    union { float f; unsigned u; } ua, ub;
    ua.f = a; ub.f = b;
    return __builtin_amdgcn_perm(ub.u + 0x8000u, ua.u + 0x8000u, 0x07060302u);
#endif
}

struct Raw { float4 p0, p1, t0, t1; };

// Fully-MFMA SSIM: h-blur = data x W (banded), v-blur = W x ring.
// Wave-private LDS ring strips -> no barriers in the loop.
// Register double-buffer prefetch hides global load latency.
// launch_bounds(256,6): 6 blocks/CU (LDS 6x26112=157KB<160KB, VGPR<=84),
// grid = exactly 6/CU -> all blocks co-resident, no tail.
__global__ __launch_bounds__(256, 6) void ssim_kernel(
    const float* __restrict__ pred, const float* __restrict__ target,
    float* __restrict__ ws_sum)
{
    // ring[wave][ch][col][slot], bf16: 4*5*16*40*2 = 25600 B
    __shared__ __align__(16) short ring[4][5][16][SLOTS];
    __shared__ float red[4];

    const int tid = threadIdx.x;
    const int wv = tid >> 6;
    const int lane = tid & 63;
    const int m = lane & 15;     // A-row / B-col / C-col index
    const int quad = lane >> 4;  // k-group / C-row-group

    // Gaussian weights, sigma=1.5
    float wsum = 0.f;
#pragma unroll
    for (int k = 0; k < KS; ++k) {
        float d = (float)(k - 5);
        wsum += __expf(-d * d * (1.0f / 4.5f));
    }
    const float invs = 1.0f / wsum;

    // Banded weight fragment: value at k=quad*8+j is w[k - m - 3] (0 outside band).
    // Serves as B in h-mfma (B[k][n]=w[k-n-3]) and A in v-mfma (A[m][k]=w[k-m-3]).
    short8 Wf;
    {
        union { short8 v; unsigned u[4]; } W;
#pragma unroll
        for (int jj = 0; jj < 4; ++jj) {
            float v0, v1;
            {
                int idx = quad * 8 + 2 * jj - m - 3;
                float d = (float)(idx - 5);
                v0 = (idx >= 0 && idx < KS) ? __expf(-d * d * (1.0f / 4.5f)) * invs : 0.f;
            }
            {
                int idx = quad * 8 + 2 * jj + 1 - m - 3;
                float d = (float)(idx - 5);
                v1 = (idx >= 0 && idx < KS) ? __expf(-d * d * (1.0f / 4.5f)) * invs : 0.f;
            }
            W.u[jj] = pk2bf_rne(v0, v1);
        }
        Wf = W.v;
    }

    const size_t poff = (size_t)blockIdx.z * HH * WW;
    const float* __restrict__ pp = pred + poff;
    const float* __restrict__ tp = target + poff;
    const int X0 = blockIdx.x * 64 + wv * 16;  // wave's 16-col tile
    const int rawX = X0 - 8;                   // 32-col raw window base
    const int Y0 = blockIdx.y * BY;

    const float C1 = 1.0e-4f;
    const float C2 = 9.0e-4f;
    float lsum = 0.f;
    const floatx4 z = {0.f, 0.f, 0.f, 0.f};

    // load chunk k's raw rows (zero-padded outside the image)
    auto load_raw = [&](int k) -> Raw {
        Raw r;
        r.p0 = make_float4(0, 0, 0, 0); r.p1 = make_float4(0, 0, 0, 0);
        r.t0 = make_float4(0, 0, 0, 0); r.t1 = make_float4(0, 0, 0, 0);
        const int row = Y0 + CHK * k - 8 + m;
        if ((unsigned)row < (unsigned)HH) {
            const float* pr = pp + (size_t)row * WW;
            const float* tr = tp + (size_t)row * WW;
            const int c0 = rawX + quad * 8;
            if ((unsigned)c0 < (unsigned)WW) {
                r.p0 = *(const float4*)(pr + c0);
                r.t0 = *(const float4*)(tr + c0);
            }
            if ((unsigned)(c0 + 4) < (unsigned)WW) {
                r.p1 = *(const float4*)(pr + c0 + 4);
                r.t1 = *(const float4*)(tr + c0 + 4);
            }
        }
        return r;
    };

    // h-step: pack raw -> bf16 frags, 5 MFMA, pack D -> ring at slot base sb
    auto h_step = [&](const Raw& r, int sb) {
        const float p[8] = {r.p0.x, r.p0.y, r.p0.z, r.p0.w,
                            r.p1.x, r.p1.y, r.p1.z, r.p1.w};
        const float t[8] = {r.t0.x, r.t0.y, r.t0.z, r.t0.w,
                            r.t1.x, r.t1.y, r.t1.z, r.t1.w};
        union { short8 v; unsigned u[4]; } Fp, Ft, Fpp, Ftt, Fpt;
#pragma unroll
        for (int jj = 0; jj < 4; ++jj) {
            const float a0 = p[2 * jj], a1 = p[2 * jj + 1];
            const float b0 = t[2 * jj], b1 = t[2 * jj + 1];
            Fp.u[jj]  = pkbf(a0, a1);
            Ft.u[jj]  = pkbf(b0, b1);
            Fpp.u[jj] = pkbf(a0 * a0, a1 * a1);
            Ftt.u[jj] = pkbf(b0 * b0, b1 * b1);
            Fpt.u[jj] = pkbf(a0 * b0, a1 * b1);
        }
        floatx4 Dp  = __builtin_amdgcn_mfma_f32_16x16x32_bf16(Fp.v,  Wf, z, 0, 0, 0);
        floatx4 Dt  = __builtin_amdgcn_mfma_f32_16x16x32_bf16(Ft.v,  Wf, z, 0, 0, 0);
        floatx4 Dpp = __builtin_amdgcn_mfma_f32_16x16x32_bf16(Fpp.v, Wf, z, 0, 0, 0);
        floatx4 Dtt = __builtin_amdgcn_mfma_f32_16x16x32_bf16(Ftt.v, Wf, z, 0, 0, 0);
        floatx4 Dpt = __builtin_amdgcn_mfma_f32_16x16x32_bf16(Fpt.v, Wf, z, 0, 0, 0);
        // C-layout: col = lane&15 (=m), rows = quad*4 + reg -> slots sb+quad*4+reg
        int slot = sb + quad * 4;
        if (slot >= SLOTS) slot -= SLOTS;
        uint2 v;
        v.x = pkbf(Dp[0], Dp[1]);   v.y = pkbf(Dp[2], Dp[3]);
        *(uint2*)&ring[wv][0][m][slot] = v;
        v.x = pkbf(Dt[0], Dt[1]);   v.y = pkbf(Dt[2], Dt[3]);
        *(uint2*)&ring[wv][1][m][slot] = v;
        v.x = pkbf(Dpp[0], Dpp[1]); v.y = pkbf(Dpp[2], Dpp[3]);
        *(uint2*)&ring[wv][2][m][slot] = v;
        v.x = pkbf(Dtt[0], Dtt[1]); v.y = pkbf(Dtt[2], Dtt[3]);
        *(uint2*)&ring[wv][3][m][slot] = v;
        v.x = pkbf(Dpt[0], Dpt[1]); v.y = pkbf(Dpt[2], Dpt[3]);
        *(uint2*)&ring[wv][4][m][slot] = v;
    };

    // v-step: consume 32-slot window starting at vb -> 16 output rows, SSIM
    auto v_step = [&](int vb) {
        int sq = vb + quad * 8;
        if (sq >= SLOTS) sq -= SLOTS;
        const short8 Bp  = *(const short8*)&ring[wv][0][m][sq];
        const short8 Bt  = *(const short8*)&ring[wv][1][m][sq];
        const short8 Bpp = *(const short8*)&ring[wv][2][m][sq];
        const short8 Btt = *(const short8*)&ring[wv][3][m][sq];
        const short8 Bpt = *(const short8*)&ring[wv][4][m][sq];
        floatx4 Mp  = __builtin_amdgcn_mfma_f32_16x16x32_bf16(Wf, Bp,  z, 0, 0, 0);
        floatx4 Mt  = __builtin_amdgcn_mfma_f32_16x16x32_bf16(Wf, Bt,  z, 0, 0, 0);
        floatx4 Mpp = __builtin_amdgcn_mfma_f32_16x16x32_bf16(Wf, Bpp, z, 0, 0, 0);
        floatx4 Mtt = __builtin_amdgcn_mfma_f32_16x16x32_bf16(Wf, Btt, z, 0, 0, 0);
        floatx4 Mpt = __builtin_amdgcn_mfma_f32_16x16x32_bf16(Wf, Bpt, z, 0, 0, 0);
#pragma unroll
        for (int r = 0; r < 4; ++r) {
            const float mup = Mp[r], mut = Mt[r];
            const float mupsq = mup * mup, mutsq = mut * mut, mucr = mup * mut;
            const float sp2 = Mpp[r] - mupsq;
            const float st2 = Mtt[r] - mutsq;
            const float scr = Mpt[r] - mucr;
            const float n1 = 2.f * mucr + C1;
            const float n2 = 2.f * scr + C2;
            const float d1 = mupsq + mutsq + C1;
            const float d2 = sp2 + st2 + C2;
            lsum += __fdividef(n1 * n2, d1 * d2);
        }
    };

    // Software pipeline with register double-buffer prefetch (rolled loop --
    // full unroll spilled to scratch in R6: WRITE_SIZE 48 KB -> 67 MB).
    Raw A = load_raw(0);
    Raw B = load_raw(1);
    int hb = SLOTS - 8;   // (-8) mod 40
    int vb = SLOTS - 8;
    h_step(A, hb);
    hb += CHK; if (hb >= SLOTS) hb -= SLOTS;
#pragma unroll 1
    for (int i = 0; i < NCH; ++i) {
        h_step(B, hb);
        hb += CHK; if (hb >= SLOTS) hb -= SLOTS;
        if (i + 2 <= NCH) B = load_raw(i + 2);   // prefetch overlaps v + next h
        v_step(vb);
        vb += CHK; if (vb >= SLOTS) vb -= SLOTS;
    }

    // wave reduce -> block reduce -> one atomic per block
#pragma unroll
    for (int off = 32; off > 0; off >>= 1) lsum += __shfl_down(lsum, off, 64);
    if (lane == 0) red[wv] = lsum;
    __syncthreads();
    if (tid == 0) {
        atomicAdd(ws_sum, red[0] + red[1] + red[2] + red[3]);
    }
}

__global__ void finalize_kernel(const float* __restrict__ ws_sum,
                                float* __restrict__ out) {
    out[0] = 1.0f - ws_sum[0] * (1.0f / 12582912.0f);  // N = 16*3*512*512
}

extern "C" void kernel_launch(void* const* d_in, const int* in_sizes, int n_in,
                              void* d_out, int out_size, void* d_ws, size_t ws_size,
                              hipStream_t stream) {
    const float* pred = (const float*)d_in[0];
    const float* target = (const float*)d_in[1];
    float* out = (float*)d_out;
    float* ws = (float*)d_ws;

    hipMemsetAsync(ws, 0, sizeof(float), stream);       // graph-capturable
    dim3 grid(WW / 64, HH / BY, NPLANE);                // 8 x 4 x 48 = 1536 blocks
    ssim_kernel<<<grid, 256, 0, stream>>>(pred, target, ws);
    finalize_kernel<<<1, 1, 0, stream>>>(ws, out);
}

// Round 9
// 140.303 us; speedup vs baseline: 1.4652x; 1.0070x over previous
//
#include <hip/hip_runtime.h>

#define HH 512
#define WW 512
#define NPLANE 48
#define BY 128
#define CHK 16
#define NCH (BY / CHK)   // 8 chunks per block
#define SLOTS 40         // ring slots per col (16B-aligned groups)
#define KS 11

typedef __attribute__((ext_vector_type(8))) short short8;   // 8 bf16 (A/B frag)
typedef __attribute__((ext_vector_type(4))) float floatx4;  // 4 fp32 (C/D frag)
typedef __attribute__((ext_vector_type(2))) float float2v;
typedef __attribute__((ext_vector_type(2))) __bf16 bf16x2v;

// exact RNE pack (weights, once)
__device__ inline unsigned pk2bf_rne(float a, float b) {
    union { float f; unsigned u; } ua, ub;
    ua.f = a; ub.f = b;
    unsigned lo = (ua.u + 0x7FFFu + ((ua.u >> 16) & 1u)) >> 16;
    unsigned hi = (ub.u + 0x7FFFu + ((ub.u >> 16) & 1u)) >> 16;
    return lo | (hi << 16);
}

// hot-path pack: float2 -> bf16x2; lowers to v_cvt_pk_bf16_f32 on gfx950
__device__ inline unsigned pkbf(float a, float b) {
    float2v f = {a, b};
    bf16x2v v = __builtin_convertvector(f, bf16x2v);
    return __builtin_bit_cast(unsigned, v);
}

struct Raw { float4 p0, p1, t0, t1; };

// Fully-MFMA SSIM: h-blur = data x W (banded), v-blur = W x ring.
// Wave-private LDS ring strips -> no barriers. Register double-buffer global
// prefetch + hoisted v-fragment ds_reads (issued a full h-step before use;
// same-wave DS in-order execution makes the WAR slot reuse safe).
__global__ __launch_bounds__(256, 4) void ssim_kernel(
    const float* __restrict__ pred, const float* __restrict__ target,
    float* __restrict__ ws_sum)
{
    // ring[wave][ch][col][slot], bf16: 4*5*16*40*2 = 25600 B
    __shared__ __align__(16) short ring[4][5][16][SLOTS];
    __shared__ float red[4];

    const int tid = threadIdx.x;
    const int wv = tid >> 6;
    const int lane = tid & 63;
    const int m = lane & 15;     // A-row / B-col / C-col index
    const int quad = lane >> 4;  // k-group / C-row-group

    // Gaussian weights, sigma=1.5
    float wsum = 0.f;
#pragma unroll
    for (int k = 0; k < KS; ++k) {
        float d = (float)(k - 5);
        wsum += __expf(-d * d * (1.0f / 4.5f));
    }
    const float invs = 1.0f / wsum;

    // Banded weight fragment: value at k=quad*8+j is w[k - m - 3] (0 outside band).
    // Serves as B in h-mfma (B[k][n]=w[k-n-3]) and A in v-mfma (A[m][k]=w[k-m-3]).
    short8 Wf;
    {
        union { short8 v; unsigned u[4]; } W;
#pragma unroll
        for (int jj = 0; jj < 4; ++jj) {
            float v0, v1;
            {
                int idx = quad * 8 + 2 * jj - m - 3;
                float d = (float)(idx - 5);
                v0 = (idx >= 0 && idx < KS) ? __expf(-d * d * (1.0f / 4.5f)) * invs : 0.f;
            }
            {
                int idx = quad * 8 + 2 * jj + 1 - m - 3;
                float d = (float)(idx - 5);
                v1 = (idx >= 0 && idx < KS) ? __expf(-d * d * (1.0f / 4.5f)) * invs : 0.f;
            }
            W.u[jj] = pk2bf_rne(v0, v1);
        }
        Wf = W.v;
    }

    const size_t poff = (size_t)blockIdx.z * HH * WW;
    const float* __restrict__ pp = pred + poff;
    const float* __restrict__ tp = target + poff;
    const int X0 = blockIdx.x * 64 + wv * 16;  // wave's 16-col tile
    const int rawX = X0 - 8;                   // 32-col raw window base
    const int Y0 = blockIdx.y * BY;

    const float C1 = 1.0e-4f;
    const float C2 = 9.0e-4f;
    float lsum = 0.f;
    const floatx4 z = {0.f, 0.f, 0.f, 0.f};

    // load chunk k's raw rows (zero-padded outside the image)
    auto load_raw = [&](int k) -> Raw {
        Raw r;
        r.p0 = make_float4(0, 0, 0, 0); r.p1 = make_float4(0, 0, 0, 0);
        r.t0 = make_float4(0, 0, 0, 0); r.t1 = make_float4(0, 0, 0, 0);
        const int row = Y0 + CHK * k - 8 + m;
        if ((unsigned)row < (unsigned)HH) {
            const float* pr = pp + (size_t)row * WW;
            const float* tr = tp + (size_t)row * WW;
            const int c0 = rawX + quad * 8;
            if ((unsigned)c0 < (unsigned)WW) {
                r.p0 = *(const float4*)(pr + c0);
                r.t0 = *(const float4*)(tr + c0);
            }
            if ((unsigned)(c0 + 4) < (unsigned)WW) {
                r.p1 = *(const float4*)(pr + c0 + 4);
                r.t1 = *(const float4*)(tr + c0 + 4);
            }
        }
        return r;
    };

    // h-step: pack raw -> bf16 frags, 5 MFMA, pack D -> ring at slot base sb
    auto h_step = [&](const Raw& r, int sb) {
        const float p[8] = {r.p0.x, r.p0.y, r.p0.z, r.p0.w,
                            r.p1.x, r.p1.y, r.p1.z, r.p1.w};
        const float t[8] = {r.t0.x, r.t0.y, r.t0.z, r.t0.w,
                            r.t1.x, r.t1.y, r.t1.z, r.t1.w};
        union { short8 v; unsigned u[4]; } Fp, Ft, Fpp, Ftt, Fpt;
#pragma unroll
        for (int jj = 0; jj < 4; ++jj) {
            const float a0 = p[2 * jj], a1 = p[2 * jj + 1];
            const float b0 = t[2 * jj], b1 = t[2 * jj + 1];
            Fp.u[jj]  = pkbf(a0, a1);
            Ft.u[jj]  = pkbf(b0, b1);
            Fpp.u[jj] = pkbf(a0 * a0, a1 * a1);
            Ftt.u[jj] = pkbf(b0 * b0, b1 * b1);
            Fpt.u[jj] = pkbf(a0 * b0, a1 * b1);
        }
        floatx4 Dp  = __builtin_amdgcn_mfma_f32_16x16x32_bf16(Fp.v,  Wf, z, 0, 0, 0);
        floatx4 Dt  = __builtin_amdgcn_mfma_f32_16x16x32_bf16(Ft.v,  Wf, z, 0, 0, 0);
        floatx4 Dpp = __builtin_amdgcn_mfma_f32_16x16x32_bf16(Fpp.v, Wf, z, 0, 0, 0);
        floatx4 Dtt = __builtin_amdgcn_mfma_f32_16x16x32_bf16(Ftt.v, Wf, z, 0, 0, 0);
        floatx4 Dpt = __builtin_amdgcn_mfma_f32_16x16x32_bf16(Fpt.v, Wf, z, 0, 0, 0);
        // C-layout: col = lane&15 (=m), rows = quad*4 + reg -> slots sb+quad*4+reg
        int slot = sb + quad * 4;
        if (slot >= SLOTS) slot -= SLOTS;
        uint2 v;
        v.x = pkbf(Dp[0], Dp[1]);   v.y = pkbf(Dp[2], Dp[3]);
        *(uint2*)&ring[wv][0][m][slot] = v;
        v.x = pkbf(Dt[0], Dt[1]);   v.y = pkbf(Dt[2], Dt[3]);
        *(uint2*)&ring[wv][1][m][slot] = v;
        v.x = pkbf(Dpp[0], Dpp[1]); v.y = pkbf(Dpp[2], Dpp[3]);
        *(uint2*)&ring[wv][2][m][slot] = v;
        v.x = pkbf(Dtt[0], Dtt[1]); v.y = pkbf(Dtt[2], Dtt[3]);
        *(uint2*)&ring[wv][3][m][slot] = v;
        v.x = pkbf(Dpt[0], Dpt[1]); v.y = pkbf(Dpt[2], Dpt[3]);
        *(uint2*)&ring[wv][4][m][slot] = v;
    };

    // Pipeline: prologue h(0),h(1); loop { read v-frags(i); h(i+2); prefetch
    // raw(i+3); v-MFMA + SSIM }. v-reads precede the aliasing h-writes in
    // program order -> in-order DS returns pre-write data (wave-private ring).
    Raw A = load_raw(0);
    Raw B = load_raw(1);
    Raw C = load_raw(2);
    h_step(A, (0 * CHK + SLOTS - 8) % SLOTS);   // 32
    h_step(B, (1 * CHK + SLOTS - 8) % SLOTS);   // 8
    int hb = (2 * CHK + SLOTS - 8) % SLOTS;     // 24
    int vb = SLOTS - 8;                         // 32
#pragma unroll 1
    for (int i = 0; i < NCH; ++i) {
        // ---- hoisted v-fragment reads (rows 16i-8 .. 16i+23) ----
        int sq = vb + quad * 8;
        if (sq >= SLOTS) sq -= SLOTS;
        const short8 Bp  = *(const short8*)&ring[wv][0][m][sq];
        const short8 Bt  = *(const short8*)&ring[wv][1][m][sq];
        const short8 Bpp = *(const short8*)&ring[wv][2][m][sq];
        const short8 Btt = *(const short8*)&ring[wv][3][m][sq];
        const short8 Bpt = *(const short8*)&ring[wv][4][m][sq];
        vb += CHK; if (vb >= SLOTS) vb -= SLOTS;

        // ---- h-blur chunk i+2 (overlaps the v-read latency) ----
        if (i + 2 <= NCH) {
            h_step(C, hb);
            hb += CHK; if (hb >= SLOTS) hb -= SLOTS;
        }
        if (i + 3 <= NCH) C = load_raw(i + 3);

        // ---- v-blur + SSIM ----
        floatx4 Mp  = __builtin_amdgcn_mfma_f32_16x16x32_bf16(Wf, Bp,  z, 0, 0, 0);
        floatx4 Mt  = __builtin_amdgcn_mfma_f32_16x16x32_bf16(Wf, Bt,  z, 0, 0, 0);
        floatx4 Mpp = __builtin_amdgcn_mfma_f32_16x16x32_bf16(Wf, Bpp, z, 0, 0, 0);
        floatx4 Mtt = __builtin_amdgcn_mfma_f32_16x16x32_bf16(Wf, Btt, z, 0, 0, 0);
        floatx4 Mpt = __builtin_amdgcn_mfma_f32_16x16x32_bf16(Wf, Bpt, z, 0, 0, 0);
#pragma unroll
        for (int r = 0; r < 4; ++r) {
            const float mup = Mp[r], mut = Mt[r];
            const float mupsq = mup * mup, mutsq = mut * mut, mucr = mup * mut;
            const float sp2 = Mpp[r] - mupsq;
            const float st2 = Mtt[r] - mutsq;
            const float scr = Mpt[r] - mucr;
            const float n1 = 2.f * mucr + C1;
            const float n2 = 2.f * scr + C2;
            const float d1 = mupsq + mutsq + C1;
            const float d2 = sp2 + st2 + C2;
            lsum += __fdividef(n1 * n2, d1 * d2);
        }
    }

    // wave reduce -> block reduce -> one atomic per block
#pragma unroll
    for (int off = 32; off > 0; off >>= 1) lsum += __shfl_down(lsum, off, 64);
    if (lane == 0) red[wv] = lsum;
    __syncthreads();
    if (tid == 0) {
        atomicAdd(ws_sum, red[0] + red[1] + red[2] + red[3]);
    }
}

__global__ void finalize_kernel(const float* __restrict__ ws_sum,
                                float* __restrict__ out) {
    out[0] = 1.0f - ws_sum[0] * (1.0f / 12582912.0f);  // N = 16*3*512*512
}

extern "C" void kernel_launch(void* const* d_in, const int* in_sizes, int n_in,
                              void* d_out, int out_size, void* d_ws, size_t ws_size,
                              hipStream_t stream) {
    const float* pred = (const float*)d_in[0];
    const float* target = (const float*)d_in[1];
    float* out = (float*)d_out;
    float* ws = (float*)d_ws;

    hipMemsetAsync(ws, 0, sizeof(float), stream);       // graph-capturable
    dim3 grid(WW / 64, HH / BY, NPLANE);                // 8 x 4 x 48 = 1536 blocks
    ssim_kernel<<<grid, 256, 0, stream>>>(pred, target, ws);
    finalize_kernel<<<1, 1, 0, stream>>>(ws, out);
}